// Round 8
// baseline (539.414 us; speedup 1.0000x reference)
//
#include <hip/hip_runtime.h>
#include <hip/hip_fp16.h>
#include <stdint.h>

#define N_NODES 20000
#define N_EDGES 320000
#define EMB     256
#define D_IN    300
#define KPAD0   320    // D_IN padded to multiple of 32
#define SPITCH  264    // LDS A-plane pitch (ushorts)
#define SP0     328    // gemm0 LDS pitch (ushorts) for K=320
#define NTILE   1250   // 16-row tiles (20000/16)
#define LOSCL   1024.0f           // lo-plane scale (avoids fp16 subnormal flush)
#define LOINV   0.0009765625f     // 1/1024

typedef __attribute__((ext_vector_type(8))) _Float16 f16x8;  // 8 fp16 (4 VGPRs)
typedef __attribute__((ext_vector_type(4))) float    f32x4;

// fp16 pair split: v ~= hi + lo*2^-10, |err| <= |v|*2^-21
static __device__ __forceinline__ void split_f16(float v, unsigned short& h, unsigned short& l) {
    __half hh = __float2half(v);
    float  r  = (v - __half2float(hh)) * LOSCL;
    __half ll = __float2half(r);
    h = __half_as_ushort(hh);
    l = __half_as_ushort(ll);
}

// ---------------- CSR build ----------------

__global__ void k_deg(const int* __restrict__ dst, int* __restrict__ deg, int e) {
    int i = blockIdx.x * 256 + threadIdx.x;
    if (i < e) atomicAdd(&deg[dst[i]], 1);
}

// single block: exclusive scan deg -> row_off, dinv = rsqrt(deg+1)
__global__ void k_scan(const int* __restrict__ deg, int* __restrict__ row_off,
                       float* __restrict__ dinv, int n) {
    __shared__ int sums[1024];
    int tid = threadIdx.x;
    const int chunk = (n + 1023) / 1024;
    int start = tid * chunk;
    int end   = start + chunk; if (end > n) end = n; if (start > n) start = n;
    int s = 0;
    for (int i = start; i < end; ++i) {
        s += deg[i];
        dinv[i] = rsqrtf((float)(deg[i] + 1));
    }
    sums[tid] = s;
    __syncthreads();
    for (int off = 1; off < 1024; off <<= 1) {
        int v = (tid >= off) ? sums[tid - off] : 0;
        __syncthreads();
        sums[tid] += v;
        __syncthreads();
    }
    int excl = (tid == 0) ? 0 : sums[tid - 1];
    for (int i = start; i < end; ++i) { row_off[i] = excl; excl += deg[i]; }
    if (tid == 1023) row_off[n] = excl;
}

__global__ void k_scatter(const int* __restrict__ src, const int* __restrict__ dst,
                          const int* __restrict__ row_off, int* __restrict__ cursor,
                          const float* __restrict__ dinv,
                          int* __restrict__ csr_src, float* __restrict__ csr_norm, int e) {
    int i = blockIdx.x * 256 + threadIdx.x;
    if (i >= e) return;
    int s = src[i], d = dst[i];
    int pos = row_off[d] + atomicAdd(&cursor[d], 1);
    csr_src[pos]  = s;
    csr_norm[pos] = dinv[s] * dinv[d];
}

// ---------------- batched weight transpose + fp16-pair split ----------------

struct WSplitArgs {
    const float* w[6];
    unsigned short* th[6];
    unsigned short* tl[6];
};

__global__ void k_wsplit_all(WSplitArgs a) {
#pragma unroll
    for (int l = 0; l < 6; ++l) {
        const int K = l ? EMB : D_IN, Kp = l ? EMB : KPAD0;
        const int tot = EMB * Kp;
        for (int idx = blockIdx.x * 256 + threadIdx.x; idx < tot; idx += gridDim.x * 256) {
            int n = idx / Kp, k = idx - n * Kp;
            float v = (k < K) ? a.w[l][k * EMB + n] : 0.f;
            unsigned short h, lo;
            split_f16(v, h, lo);
            a.th[l][idx] = h; a.tl[l][idx] = lo;
        }
    }
}

// ---------------- GEMM building blocks (f16 MFMA) ----------------
// mfma_f32_16x16x32_f16 layouts (same as bf16 variant, HW-verified):
//   A: row = lane&15, k = (lane>>4)*8 + j
//   B: col = lane&15, k = (lane>>4)*8 + j   (rows of W^T)
//   C/D: col = lane&15, row = (lane>>4)*4 + reg
// Weights are fp16 pairs (hi, lo*2^10); result = acc0 + acc1*2^-10.

static __device__ __forceinline__ void loadB(const unsigned short* __restrict__ Wth,
                                             const unsigned short* __restrict__ Wtl,
                                             int Kpad, int k0, int wave, int l16,
                                             f16x8 bh[4], f16x8 bl[4]) {
#pragma unroll
    for (int nt = 0; nt < 4; ++nt) {
        int nn = wave * 64 + nt * 16 + l16;
        bh[nt] = *(const f16x8*)(Wth + (size_t)nn * Kpad + k0);
        bl[nt] = *(const f16x8*)(Wtl + (size_t)nn * Kpad + k0);
    }
}

// 16-row tile GEMM, A = single fp16 plane in LDS (K=EMB)
static __device__ __forceinline__ void gemm_lds16(
    const unsigned short (*Sh)[SPITCH],
    const unsigned short* __restrict__ Wth, const unsigned short* __restrict__ Wtl,
    int wave, int quad, int l16, f32x4 acc0[4], f32x4 acc1[4])
{
#pragma unroll
    for (int nt = 0; nt < 4; ++nt) {
        acc0[nt] = (f32x4){0.f, 0.f, 0.f, 0.f};
        acc1[nt] = (f32x4){0.f, 0.f, 0.f, 0.f};
    }
#pragma unroll 4
    for (int ks = 0; ks < EMB / 32; ++ks) {
        int k0 = ks * 32 + quad * 8;
        f16x8 bh[4], bl[4];
        loadB(Wth, Wtl, EMB, k0, wave, l16, bh, bl);
        f16x8 ah = *(const f16x8*)&Sh[l16][k0];
#pragma unroll
        for (int nt = 0; nt < 4; ++nt) {
            acc0[nt] = __builtin_amdgcn_mfma_f32_16x16x32_f16(ah, bh[nt], acc0[nt], 0, 0, 0);
            acc1[nt] = __builtin_amdgcn_mfma_f32_16x16x32_f16(ah, bl[nt], acc1[nt], 0, 0, 0);
        }
    }
}

// ---------------- conv0 GEMM: x[20000x300] @ W0 -> H (fp16) ----------------
// A staged as fp16 pair (x is f32; pair keeps 2^-21 accuracy on layer 0)

__global__ __launch_bounds__(256, 4) void k_gemm0(
    const float* __restrict__ x,
    const unsigned short* __restrict__ Wth, const unsigned short* __restrict__ Wtl,
    __half* __restrict__ H)
{
    __shared__ unsigned short Sh[16][SP0];
    __shared__ unsigned short Sl[16][SP0];
    int tid  = threadIdx.x;
    int lane = tid & 63, wave = tid >> 6;
    int quad = lane >> 4, l16 = lane & 15;
    int m_base = blockIdx.x * 16;

    for (int i = tid; i < 16 * KPAD0; i += 256) {
        int r = i / KPAD0, k = i - r * KPAD0;
        float v = (k < D_IN) ? x[(size_t)(m_base + r) * D_IN + k] : 0.f;
        unsigned short h, lo;
        split_f16(v, h, lo);
        Sh[r][k] = h; Sl[r][k] = lo;
    }
    __syncthreads();

    f32x4 acc0[4], acc1[4];
#pragma unroll
    for (int nt = 0; nt < 4; ++nt) {
        acc0[nt] = (f32x4){0.f, 0.f, 0.f, 0.f};
        acc1[nt] = (f32x4){0.f, 0.f, 0.f, 0.f};
    }
#pragma unroll 2
    for (int ks = 0; ks < KPAD0 / 32; ++ks) {
        int k0 = ks * 32 + quad * 8;
        f16x8 bh[4], bl[4];
        loadB(Wth, Wtl, KPAD0, k0, wave, l16, bh, bl);
        f16x8 ah = *(const f16x8*)&Sh[l16][k0];
        f16x8 al = *(const f16x8*)&Sl[l16][k0];
#pragma unroll
        for (int nt = 0; nt < 4; ++nt) {
            acc0[nt] = __builtin_amdgcn_mfma_f32_16x16x32_f16(ah, bh[nt], acc0[nt], 0, 0, 0);
            acc1[nt] = __builtin_amdgcn_mfma_f32_16x16x32_f16(ah, bl[nt], acc1[nt], 0, 0, 0);
            acc1[nt] = __builtin_amdgcn_mfma_f32_16x16x32_f16(al, bh[nt], acc1[nt], 0, 0, 0);
        }
    }

#pragma unroll
    for (int r = 0; r < 4; ++r) {
        int row = m_base + quad * 4 + r;
#pragma unroll
        for (int nt = 0; nt < 4; ++nt) {
            int col = wave * 64 + nt * 16 + l16;
            H[(size_t)row * EMB + col] = __float2half(acc0[nt][r] + acc1[nt][r] * LOINV);
        }
    }
}

// ---------------- agg phase: 16 nodes -> LDS fp16 plane ----------------
// wave handles 4 nodes serially; lane owns 4 dims; 8 gathers in flight.

static __device__ __forceinline__ void agg_tile(
    unsigned short (*Sh)[SPITCH],
    int nb, int wave, int lane,
    const __half* __restrict__ Fin,
    const int* __restrict__ row_off, const int* __restrict__ csr_src,
    const float* __restrict__ csr_norm, const float* __restrict__ dinv,
    const float* __restrict__ bagg, int relu)
{
    const int d0 = lane * 4;
    float4 bb = *(const float4*)(bagg + d0);

    auto load4 = [&](int row) -> float4 {
        uint2 u = *(const uint2*)(Fin + (size_t)row * EMB + d0);
        __half2 p0 = *(__half2*)&u.x;
        __half2 p1 = *(__half2*)&u.y;
        float2 f0 = __half22float2(p0);
        float2 f1 = __half22float2(p1);
        float4 r; r.x = f0.x; r.y = f0.y; r.z = f1.x; r.w = f1.y;
        return r;
    };

#pragma unroll
    for (int t = 0; t < 4; ++t) {
        int node = nb + wave * 4 + t;
        float dv = dinv[node];
        float ws = dv * dv;
        float4 sv = load4(node);
        float a0 = bb.x + ws * sv.x;
        float a1 = bb.y + ws * sv.y;
        float a2 = bb.z + ws * sv.z;
        float a3 = bb.w + ws * sv.w;
        int j = row_off[node], je = row_off[node + 1];
        for (; j + 7 < je; j += 8) {
            int   s[8]; float w[8]; float4 v[8];
#pragma unroll
            for (int q = 0; q < 8; ++q) { s[q] = csr_src[j + q]; w[q] = csr_norm[j + q]; }
#pragma unroll
            for (int q = 0; q < 8; ++q) v[q] = load4(s[q]);
#pragma unroll
            for (int q = 0; q < 8; ++q) {
                a0 += w[q] * v[q].x; a1 += w[q] * v[q].y;
                a2 += w[q] * v[q].z; a3 += w[q] * v[q].w;
            }
        }
        for (; j + 3 < je; j += 4) {
            int   s[4]; float w[4]; float4 v[4];
#pragma unroll
            for (int q = 0; q < 4; ++q) { s[q] = csr_src[j + q]; w[q] = csr_norm[j + q]; }
#pragma unroll
            for (int q = 0; q < 4; ++q) v[q] = load4(s[q]);
#pragma unroll
            for (int q = 0; q < 4; ++q) {
                a0 += w[q] * v[q].x; a1 += w[q] * v[q].y;
                a2 += w[q] * v[q].z; a3 += w[q] * v[q].w;
            }
        }
        for (; j < je; ++j) {
            int   s = csr_src[j];
            float w = csr_norm[j];
            float4 v = load4(s);
            a0 += w * v.x; a1 += w * v.y; a2 += w * v.z; a3 += w * v.w;
        }
        if (relu) {
            a0 = fmaxf(a0, 0.f); a1 = fmaxf(a1, 0.f);
            a2 = fmaxf(a2, 0.f); a3 = fmaxf(a3, 0.f);
        }
        ushort4 o;
        o.x = __half_as_ushort(__float2half(a0));
        o.y = __half_as_ushort(__float2half(a1));
        o.z = __half_as_ushort(__float2half(a2));
        o.w = __half_as_ushort(__float2half(a3));
        *(ushort4*)&Sh[wave * 4 + t][d0] = o;
    }
}

// ---------------- fused conv: agg(Fin)+bias,relu -> LDS -> @W -> Fout fp16 ----------------

__global__ __launch_bounds__(256, 4) void k_conv_fused(
    const __half* __restrict__ Fin,
    const int* __restrict__ row_off, const int* __restrict__ csr_src,
    const float* __restrict__ csr_norm, const float* __restrict__ dinv,
    const float* __restrict__ bagg,
    const unsigned short* __restrict__ Wth, const unsigned short* __restrict__ Wtl,
    __half* __restrict__ Fout)
{
    __shared__ unsigned short Sh[16][SPITCH];
    int tid  = threadIdx.x;
    int lane = tid & 63, wave = tid >> 6;
    int quad = lane >> 4, l16 = lane & 15;
    int nb   = blockIdx.x * 16;

    agg_tile(Sh, nb, wave, lane, Fin, row_off, csr_src, csr_norm, dinv, bagg, 1);
    __syncthreads();

    f32x4 acc0[4], acc1[4];
    gemm_lds16(Sh, Wth, Wtl, wave, quad, l16, acc0, acc1);

#pragma unroll
    for (int r = 0; r < 4; ++r) {
        int row = nb + quad * 4 + r;
#pragma unroll
        for (int nt = 0; nt < 4; ++nt) {
            int col = wave * 64 + nt * 16 + l16;
            Fout[(size_t)row * EMB + col] = __float2half(acc0[nt][r] + acc1[nt][r] * LOINV);
        }
    }
}

// ---------------- fused tail: agg(Fin)+b2 -> mlp1 -> mlp2 -> mlp3 -> out ----------------

__global__ __launch_bounds__(256, 4) void k_mlp_fused(
    const __half* __restrict__ Fin,
    const int* __restrict__ row_off, const int* __restrict__ csr_src,
    const float* __restrict__ csr_norm, const float* __restrict__ dinv,
    const float* __restrict__ bagg,
    const unsigned short* __restrict__ Wth3, const unsigned short* __restrict__ Wtl3,
    const float* __restrict__ b3,
    const unsigned short* __restrict__ Wth4, const unsigned short* __restrict__ Wtl4,
    const float* __restrict__ b4,
    const unsigned short* __restrict__ Wth5, const unsigned short* __restrict__ Wtl5,
    const float* __restrict__ b5,
    float* __restrict__ out)
{
    __shared__ unsigned short Sh[16][SPITCH];
    int tid  = threadIdx.x;
    int lane = tid & 63, wave = tid >> 6;
    int quad = lane >> 4, l16 = lane & 15;
    int nb   = blockIdx.x * 16;

    agg_tile(Sh, nb, wave, lane, Fin, row_off, csr_src, csr_norm, dinv, bagg, 0);
    __syncthreads();

    f32x4 acc0[4], acc1[4];

    // mlp1: relu(S @ W3 + b3) -> S
    gemm_lds16(Sh, Wth3, Wtl3, wave, quad, l16, acc0, acc1);
    __syncthreads();
#pragma unroll
    for (int r = 0; r < 4; ++r) {
        int row = quad * 4 + r;
#pragma unroll
        for (int nt = 0; nt < 4; ++nt) {
            int col = wave * 64 + nt * 16 + l16;
            float v = fmaxf(acc0[nt][r] + acc1[nt][r] * LOINV + b3[col], 0.f);
            Sh[row][col] = __half_as_ushort(__float2half(v));
        }
    }
    __syncthreads();

    // mlp2: relu(S @ W4 + b4) -> S
    gemm_lds16(Sh, Wth4, Wtl4, wave, quad, l16, acc0, acc1);
    __syncthreads();
#pragma unroll
    for (int r = 0; r < 4; ++r) {
        int row = quad * 4 + r;
#pragma unroll
        for (int nt = 0; nt < 4; ++nt) {
            int col = wave * 64 + nt * 16 + l16;
            float v = fmaxf(acc0[nt][r] + acc1[nt][r] * LOINV + b4[col], 0.f);
            Sh[row][col] = __half_as_ushort(__float2half(v));
        }
    }
    __syncthreads();

    // mlp3: S @ W5 + b5 -> out (f32)
    gemm_lds16(Sh, Wth5, Wtl5, wave, quad, l16, acc0, acc1);
#pragma unroll
    for (int r = 0; r < 4; ++r) {
        int row = nb + quad * 4 + r;
#pragma unroll
        for (int nt = 0; nt < 4; ++nt) {
            int col = wave * 64 + nt * 16 + l16;
            out[(size_t)row * EMB + col] = acc0[nt][r] + acc1[nt][r] * LOINV + b5[col];
        }
    }
}

// ---------------- launch: 1 memset + 8 dispatches ----------------

extern "C" void kernel_launch(void* const* d_in, const int* in_sizes, int n_in,
                              void* d_out, int out_size, void* d_ws, size_t ws_size,
                              hipStream_t stream) {
    const float* x  = (const float*)d_in[0];
    const int*   ei = (const int*)d_in[1];
    const int* src = ei;
    const int* dst = ei + N_EDGES;

    const float* w[6];
    const float* b[6];
    for (int i = 0; i < 6; ++i) {
        w[i] = (const float*)d_in[2 + 2 * i];
        b[i] = (const float*)d_in[3 + 2 * i];
    }

    char* wsp = (char*)d_ws;
    auto alloc = [&](size_t bytes) {
        char* p = wsp; wsp += (bytes + 255) & ~(size_t)255; return p;
    };
    int*   deg      = (int*)alloc(N_NODES * 4);
    int*   cursor   = (int*)alloc(N_NODES * 4);
    int*   row_off  = (int*)alloc((N_NODES + 1) * 4);
    int*   csr_src  = (int*)alloc(N_EDGES * 4);
    float* csr_norm = (float*)alloc(N_EDGES * 4);
    float* dinv     = (float*)alloc(N_NODES * 4);
    unsigned short* wth[6];
    unsigned short* wtl[6];
    wth[0] = (unsigned short*)alloc(EMB * KPAD0 * 2);
    wtl[0] = (unsigned short*)alloc(EMB * KPAD0 * 2);
    for (int i = 1; i < 6; ++i) {
        wth[i] = (unsigned short*)alloc(EMB * EMB * 2);
        wtl[i] = (unsigned short*)alloc(EMB * EMB * 2);
    }
    __half* FA = (__half*)alloc((size_t)N_NODES * EMB * 2);   // fp16 activation tables
    __half* FB = (__half*)alloc((size_t)N_NODES * EMB * 2);
    float*  O  = (float*)d_out;

    // zero deg + cursor in one async memset (adjacent in ws)
    size_t zspan = (size_t)((char*)row_off - (char*)deg);
    hipMemsetAsync(deg, 0, zspan, stream);

    const int NB_E = (N_EDGES + 255) / 256;   // 1250

    k_deg<<<NB_E, 256, 0, stream>>>(dst, deg, N_EDGES);
    k_scan<<<1, 1024, 0, stream>>>(deg, row_off, dinv, N_NODES);
    k_scatter<<<NB_E, 256, 0, stream>>>(src, dst, row_off, cursor, dinv,
                                        csr_src, csr_norm, N_EDGES);

    WSplitArgs wa;
    for (int i = 0; i < 6; ++i) { wa.w[i] = w[i]; wa.th[i] = wth[i]; wa.tl[i] = wtl[i]; }
    k_wsplit_all<<<512, 256, 0, stream>>>(wa);

    // conv0 gemm: x @ W0 -> FA (fp16)
    k_gemm0<<<NTILE, 256, 0, stream>>>(x, wth[0], wtl[0], FA);
    // conv1: agg(FA)+b0,relu -> @W1 -> FB
    k_conv_fused<<<NTILE, 256, 0, stream>>>(FA, row_off, csr_src, csr_norm, dinv,
                                            b[0], wth[1], wtl[1], FB);
    // conv2: agg(FB)+b1,relu -> @W2 -> FA
    k_conv_fused<<<NTILE, 256, 0, stream>>>(FB, row_off, csr_src, csr_norm, dinv,
                                            b[1], wth[2], wtl[2], FA);
    // tail: agg(FA)+b2 -> mlp1(relu) -> mlp2(relu) -> mlp3 -> d_out
    k_mlp_fused<<<NTILE, 256, 0, stream>>>(FA, row_off, csr_src, csr_norm, dinv,
                                           b[2],
                                           wth[3], wtl[3], b[3],
                                           wth[4], wtl[4], b[4],
                                           wth[5], wtl[5], b[5],
                                           O);
}

// Round 9
// 511.089 us; speedup vs baseline: 1.0554x; 1.0554x over previous
//
#include <hip/hip_runtime.h>
#include <hip/hip_fp16.h>
#include <stdint.h>

#define N_NODES 20000
#define N_EDGES 320000
#define EMB     256
#define D_IN    300
#define KPAD0   320    // D_IN padded to multiple of 32
#define SPITCH  264    // LDS A-plane pitch (ushorts)
#define SP0     328    // gemm0 LDS pitch (ushorts) for K=320
#define NTILE   1250   // 16-row tiles (20000/16)
#define LOSCL   1024.0f           // lo-plane scale (avoids fp16 subnormal flush)
#define LOINV   0.0009765625f     // 1/1024

typedef __attribute__((ext_vector_type(8))) _Float16 f16x8;  // 8 fp16 (4 VGPRs)
typedef __attribute__((ext_vector_type(4))) float    f32x4;

// fp16 pair split: v ~= hi + lo*2^-10, |err| <= |v|*2^-21
static __device__ __forceinline__ void split_f16(float v, unsigned short& h, unsigned short& l) {
    __half hh = __float2half(v);
    float  r  = (v - __half2float(hh)) * LOSCL;
    __half ll = __float2half(r);
    h = __half_as_ushort(hh);
    l = __half_as_ushort(ll);
}

// ---------------- CSR build ----------------

__global__ void k_deg(const int* __restrict__ dst, int* __restrict__ deg, int e) {
    int i = blockIdx.x * 256 + threadIdx.x;
    if (i < e) atomicAdd(&deg[dst[i]], 1);
}

// single block: exclusive scan deg -> row_off, dinv = rsqrt(deg+1)
__global__ void k_scan(const int* __restrict__ deg, int* __restrict__ row_off,
                       float* __restrict__ dinv, int n) {
    __shared__ int sums[1024];
    int tid = threadIdx.x;
    const int chunk = (n + 1023) / 1024;
    int start = tid * chunk;
    int end   = start + chunk; if (end > n) end = n; if (start > n) start = n;
    int s = 0;
    for (int i = start; i < end; ++i) {
        s += deg[i];
        dinv[i] = rsqrtf((float)(deg[i] + 1));
    }
    sums[tid] = s;
    __syncthreads();
    for (int off = 1; off < 1024; off <<= 1) {
        int v = (tid >= off) ? sums[tid - off] : 0;
        __syncthreads();
        sums[tid] += v;
        __syncthreads();
    }
    int excl = (tid == 0) ? 0 : sums[tid - 1];
    for (int i = start; i < end; ++i) { row_off[i] = excl; excl += deg[i]; }
    if (tid == 1023) row_off[n] = excl;
}

__global__ void k_scatter(const int* __restrict__ src, const int* __restrict__ dst,
                          const int* __restrict__ row_off, int* __restrict__ cursor,
                          const float* __restrict__ dinv,
                          int* __restrict__ csr_src, float* __restrict__ csr_norm, int e) {
    int i = blockIdx.x * 256 + threadIdx.x;
    if (i >= e) return;
    int s = src[i], d = dst[i];
    int pos = row_off[d] + atomicAdd(&cursor[d], 1);
    csr_src[pos]  = s;
    csr_norm[pos] = dinv[s] * dinv[d];
}

// ---------------- batched weight transpose + fp16-pair split ----------------

struct WSplitArgs {
    const float* w[6];
    unsigned short* th[6];
    unsigned short* tl[6];
};

__global__ void k_wsplit_all(WSplitArgs a) {
#pragma unroll
    for (int l = 0; l < 6; ++l) {
        const int K = l ? EMB : D_IN, Kp = l ? EMB : KPAD0;
        const int tot = EMB * Kp;
        for (int idx = blockIdx.x * 256 + threadIdx.x; idx < tot; idx += gridDim.x * 256) {
            int n = idx / Kp, k = idx - n * Kp;
            float v = (k < K) ? a.w[l][k * EMB + n] : 0.f;
            unsigned short h, lo;
            split_f16(v, h, lo);
            a.th[l][idx] = h; a.tl[l][idx] = lo;
        }
    }
}

// ---------------- GEMM building blocks (f16 MFMA) ----------------
// mfma_f32_16x16x32_f16 layouts (HW-verified):
//   A: row = lane&15, k = (lane>>4)*8 + j
//   B: col = lane&15, k = (lane>>4)*8 + j   (rows of W^T)
//   C/D: col = lane&15, row = (lane>>4)*4 + reg
// Weights fp16 pairs (hi, lo*2^10); result = acc0 + acc1*2^-10.

static __device__ __forceinline__ void loadB(const unsigned short* __restrict__ Wth,
                                             const unsigned short* __restrict__ Wtl,
                                             int Kpad, int k0, int wave, int l16,
                                             f16x8 bh[4], f16x8 bl[4]) {
#pragma unroll
    for (int nt = 0; nt < 4; ++nt) {
        int nn = wave * 64 + nt * 16 + l16;
        bh[nt] = *(const f16x8*)(Wth + (size_t)nn * Kpad + k0);
        bl[nt] = *(const f16x8*)(Wtl + (size_t)nn * Kpad + k0);
    }
}

// 16-row tile GEMM, A read directly from global fp16 table (row-major, EMB cols)
static __device__ __forceinline__ void gemm_globalA(
    const __half* __restrict__ A, int m_base,
    const unsigned short* __restrict__ Wth, const unsigned short* __restrict__ Wtl,
    int wave, int quad, int l16, f32x4 acc0[4], f32x4 acc1[4])
{
#pragma unroll
    for (int nt = 0; nt < 4; ++nt) {
        acc0[nt] = (f32x4){0.f, 0.f, 0.f, 0.f};
        acc1[nt] = (f32x4){0.f, 0.f, 0.f, 0.f};
    }
    const unsigned short* Au = (const unsigned short*)A;
#pragma unroll 2
    for (int ks = 0; ks < EMB / 32; ++ks) {
        int k0 = ks * 32 + quad * 8;
        f16x8 bh[4], bl[4];
        loadB(Wth, Wtl, EMB, k0, wave, l16, bh, bl);
        f16x8 ah = *(const f16x8*)(Au + (size_t)(m_base + l16) * EMB + k0);
#pragma unroll
        for (int nt = 0; nt < 4; ++nt) {
            acc0[nt] = __builtin_amdgcn_mfma_f32_16x16x32_f16(ah, bh[nt], acc0[nt], 0, 0, 0);
            acc1[nt] = __builtin_amdgcn_mfma_f32_16x16x32_f16(ah, bl[nt], acc1[nt], 0, 0, 0);
        }
    }
}

// 16-row tile GEMM, A = fp16 plane in LDS
static __device__ __forceinline__ void gemm_ldsA(
    const unsigned short (*Sh)[SPITCH],
    const unsigned short* __restrict__ Wth, const unsigned short* __restrict__ Wtl,
    int wave, int quad, int l16, f32x4 acc0[4], f32x4 acc1[4])
{
#pragma unroll
    for (int nt = 0; nt < 4; ++nt) {
        acc0[nt] = (f32x4){0.f, 0.f, 0.f, 0.f};
        acc1[nt] = (f32x4){0.f, 0.f, 0.f, 0.f};
    }
#pragma unroll 2
    for (int ks = 0; ks < EMB / 32; ++ks) {
        int k0 = ks * 32 + quad * 8;
        f16x8 bh[4], bl[4];
        loadB(Wth, Wtl, EMB, k0, wave, l16, bh, bl);
        f16x8 ah = *(const f16x8*)&Sh[l16][k0];
#pragma unroll
        for (int nt = 0; nt < 4; ++nt) {
            acc0[nt] = __builtin_amdgcn_mfma_f32_16x16x32_f16(ah, bh[nt], acc0[nt], 0, 0, 0);
            acc1[nt] = __builtin_amdgcn_mfma_f32_16x16x32_f16(ah, bl[nt], acc1[nt], 0, 0, 0);
        }
    }
}

// ---------------- conv0 GEMM: x[20000x300] @ W0 -> H (fp16) ----------------

__global__ __launch_bounds__(256, 4) void k_gemm0(
    const float* __restrict__ x,
    const unsigned short* __restrict__ Wth, const unsigned short* __restrict__ Wtl,
    __half* __restrict__ H)
{
    __shared__ unsigned short Sh[16][SP0];
    __shared__ unsigned short Sl[16][SP0];
    int tid  = threadIdx.x;
    int lane = tid & 63, wave = tid >> 6;
    int quad = lane >> 4, l16 = lane & 15;
    int m_base = blockIdx.x * 16;

    for (int i = tid; i < 16 * KPAD0; i += 256) {
        int r = i / KPAD0, k = i - r * KPAD0;
        float v = (k < D_IN) ? x[(size_t)(m_base + r) * D_IN + k] : 0.f;
        unsigned short h, lo;
        split_f16(v, h, lo);
        Sh[r][k] = h; Sl[r][k] = lo;
    }
    __syncthreads();

    f32x4 acc0[4], acc1[4];
#pragma unroll
    for (int nt = 0; nt < 4; ++nt) {
        acc0[nt] = (f32x4){0.f, 0.f, 0.f, 0.f};
        acc1[nt] = (f32x4){0.f, 0.f, 0.f, 0.f};
    }
#pragma unroll 2
    for (int ks = 0; ks < KPAD0 / 32; ++ks) {
        int k0 = ks * 32 + quad * 8;
        f16x8 bh[4], bl[4];
        loadB(Wth, Wtl, KPAD0, k0, wave, l16, bh, bl);
        f16x8 ah = *(const f16x8*)&Sh[l16][k0];
        f16x8 al = *(const f16x8*)&Sl[l16][k0];
#pragma unroll
        for (int nt = 0; nt < 4; ++nt) {
            acc0[nt] = __builtin_amdgcn_mfma_f32_16x16x32_f16(ah, bh[nt], acc0[nt], 0, 0, 0);
            acc1[nt] = __builtin_amdgcn_mfma_f32_16x16x32_f16(ah, bl[nt], acc1[nt], 0, 0, 0);
            acc1[nt] = __builtin_amdgcn_mfma_f32_16x16x32_f16(al, bh[nt], acc1[nt], 0, 0, 0);
        }
    }

#pragma unroll
    for (int r = 0; r < 4; ++r) {
        int row = m_base + quad * 4 + r;
#pragma unroll
        for (int nt = 0; nt < 4; ++nt) {
            int col = wave * 64 + nt * 16 + l16;
            H[(size_t)row * EMB + col] = __float2half(acc0[nt][r] + acc1[nt][r] * LOINV);
        }
    }
}

// ---------------- standalone agg: wave-per-node, BW-bound regime ----------------
// 5000 blocks x 4 waves; one wave owns one full fp16 row (8B/lane).
// out = bias + dinv^2*h[node] + sum norm*h[src]; optional relu; fp16 out.

__global__ __launch_bounds__(256) void k_agg(
    const __half* __restrict__ Fin,
    const int* __restrict__ row_off, const int* __restrict__ csr_src,
    const float* __restrict__ csr_norm, const float* __restrict__ dinv,
    const float* __restrict__ bagg, int relu,
    __half* __restrict__ Gout)
{
    int node = blockIdx.x * 4 + (threadIdx.x >> 6);
    if (node >= N_NODES) return;
    int lane = threadIdx.x & 63;
    const int d0 = lane * 4;

    auto load4 = [&](int row) -> float4 {
        uint2 u = *(const uint2*)(Fin + (size_t)row * EMB + d0);
        __half2 p0 = *(__half2*)&u.x;
        __half2 p1 = *(__half2*)&u.y;
        float2 f0 = __half22float2(p0);
        float2 f1 = __half22float2(p1);
        float4 r; r.x = f0.x; r.y = f0.y; r.z = f1.x; r.w = f1.y;
        return r;
    };

    float4 bb = *(const float4*)(bagg + d0);
    float dv = dinv[node];
    float ws = dv * dv;
    float4 sv = load4(node);
    float a0 = bb.x + ws * sv.x;
    float a1 = bb.y + ws * sv.y;
    float a2 = bb.z + ws * sv.z;
    float a3 = bb.w + ws * sv.w;

    int j = row_off[node], je = row_off[node + 1];
    for (; j + 3 < je; j += 4) {
        int   s0 = csr_src[j],      s1 = csr_src[j + 1];
        int   s2 = csr_src[j + 2],  s3 = csr_src[j + 3];
        float w0 = csr_norm[j],     w1 = csr_norm[j + 1];
        float w2 = csr_norm[j + 2], w3 = csr_norm[j + 3];
        float4 v0 = load4(s0);
        float4 v1 = load4(s1);
        float4 v2 = load4(s2);
        float4 v3 = load4(s3);
        a0 += w0 * v0.x + w1 * v1.x + w2 * v2.x + w3 * v3.x;
        a1 += w0 * v0.y + w1 * v1.y + w2 * v2.y + w3 * v3.y;
        a2 += w0 * v0.z + w1 * v1.z + w2 * v2.z + w3 * v3.z;
        a3 += w0 * v0.w + w1 * v1.w + w2 * v2.w + w3 * v3.w;
    }
    for (; j < je; ++j) {
        int   s = csr_src[j];
        float w = csr_norm[j];
        float4 v = load4(s);
        a0 += w * v.x; a1 += w * v.y; a2 += w * v.z; a3 += w * v.w;
    }
    if (relu) {
        a0 = fmaxf(a0, 0.f); a1 = fmaxf(a1, 0.f);
        a2 = fmaxf(a2, 0.f); a3 = fmaxf(a3, 0.f);
    }
    ushort4 o;
    o.x = __half_as_ushort(__float2half(a0));
    o.y = __half_as_ushort(__float2half(a1));
    o.z = __half_as_ushort(__float2half(a2));
    o.w = __half_as_ushort(__float2half(a3));
    *(ushort4*)((unsigned short*)Gout + (size_t)node * EMB + d0) = o;
}

// ---------------- conv GEMM: G @ W -> Fout fp16 (A direct from global, no LDS) ----------------

__global__ __launch_bounds__(256, 4) void k_gemm(
    const __half* __restrict__ G,
    const unsigned short* __restrict__ Wth, const unsigned short* __restrict__ Wtl,
    __half* __restrict__ Fout)
{
    int tid  = threadIdx.x;
    int lane = tid & 63, wave = tid >> 6;
    int quad = lane >> 4, l16 = lane & 15;
    int m_base = blockIdx.x * 16;

    f32x4 acc0[4], acc1[4];
    gemm_globalA(G, m_base, Wth, Wtl, wave, quad, l16, acc0, acc1);

#pragma unroll
    for (int r = 0; r < 4; ++r) {
        int row = m_base + quad * 4 + r;
#pragma unroll
        for (int nt = 0; nt < 4; ++nt) {
            int col = wave * 64 + nt * 16 + l16;
            Fout[(size_t)row * EMB + col] = __float2half(acc0[nt][r] + acc1[nt][r] * LOINV);
        }
    }
}

// ---------------- MLP tail: G -> mlp1 -> LDS -> mlp2 -> LDS -> mlp3 -> out f32 ----------------

__global__ __launch_bounds__(256, 4) void k_mlp3(
    const __half* __restrict__ G,
    const unsigned short* __restrict__ Wth3, const unsigned short* __restrict__ Wtl3,
    const float* __restrict__ b3,
    const unsigned short* __restrict__ Wth4, const unsigned short* __restrict__ Wtl4,
    const float* __restrict__ b4,
    const unsigned short* __restrict__ Wth5, const unsigned short* __restrict__ Wtl5,
    const float* __restrict__ b5,
    float* __restrict__ out)
{
    __shared__ unsigned short Sh[16][SPITCH];
    int tid  = threadIdx.x;
    int lane = tid & 63, wave = tid >> 6;
    int quad = lane >> 4, l16 = lane & 15;
    int nb   = blockIdx.x * 16;

    f32x4 acc0[4], acc1[4];

    // mlp1: relu(G @ W3 + b3) -> LDS
    gemm_globalA(G, nb, Wth3, Wtl3, wave, quad, l16, acc0, acc1);
#pragma unroll
    for (int r = 0; r < 4; ++r) {
        int row = quad * 4 + r;
#pragma unroll
        for (int nt = 0; nt < 4; ++nt) {
            int col = wave * 64 + nt * 16 + l16;
            float v = fmaxf(acc0[nt][r] + acc1[nt][r] * LOINV + b3[col], 0.f);
            Sh[row][col] = __half_as_ushort(__float2half(v));
        }
    }
    __syncthreads();

    // mlp2: relu(S @ W4 + b4) -> LDS
    gemm_ldsA(Sh, Wth4, Wtl4, wave, quad, l16, acc0, acc1);
    __syncthreads();
#pragma unroll
    for (int r = 0; r < 4; ++r) {
        int row = quad * 4 + r;
#pragma unroll
        for (int nt = 0; nt < 4; ++nt) {
            int col = wave * 64 + nt * 16 + l16;
            float v = fmaxf(acc0[nt][r] + acc1[nt][r] * LOINV + b4[col], 0.f);
            Sh[row][col] = __half_as_ushort(__float2half(v));
        }
    }
    __syncthreads();

    // mlp3: S @ W5 + b5 -> out (f32)
    gemm_ldsA(Sh, Wth5, Wtl5, wave, quad, l16, acc0, acc1);
#pragma unroll
    for (int r = 0; r < 4; ++r) {
        int row = nb + quad * 4 + r;
#pragma unroll
        for (int nt = 0; nt < 4; ++nt) {
            int col = wave * 64 + nt * 16 + l16;
            out[(size_t)row * EMB + col] = acc0[nt][r] + acc1[nt][r] * LOINV + b5[col];
        }
    }
}

// ---------------- launch: 1 memset + 11 dispatches ----------------

extern "C" void kernel_launch(void* const* d_in, const int* in_sizes, int n_in,
                              void* d_out, int out_size, void* d_ws, size_t ws_size,
                              hipStream_t stream) {
    const float* x  = (const float*)d_in[0];
    const int*   ei = (const int*)d_in[1];
    const int* src = ei;
    const int* dst = ei + N_EDGES;

    const float* w[6];
    const float* b[6];
    for (int i = 0; i < 6; ++i) {
        w[i] = (const float*)d_in[2 + 2 * i];
        b[i] = (const float*)d_in[3 + 2 * i];
    }

    char* wsp = (char*)d_ws;
    auto alloc = [&](size_t bytes) {
        char* p = wsp; wsp += (bytes + 255) & ~(size_t)255; return p;
    };
    int*   deg      = (int*)alloc(N_NODES * 4);
    int*   cursor   = (int*)alloc(N_NODES * 4);
    int*   row_off  = (int*)alloc((N_NODES + 1) * 4);
    int*   csr_src  = (int*)alloc(N_EDGES * 4);
    float* csr_norm = (float*)alloc(N_EDGES * 4);
    float* dinv     = (float*)alloc(N_NODES * 4);
    unsigned short* wth[6];
    unsigned short* wtl[6];
    wth[0] = (unsigned short*)alloc(EMB * KPAD0 * 2);
    wtl[0] = (unsigned short*)alloc(EMB * KPAD0 * 2);
    for (int i = 1; i < 6; ++i) {
        wth[i] = (unsigned short*)alloc(EMB * EMB * 2);
        wtl[i] = (unsigned short*)alloc(EMB * EMB * 2);
    }
    __half* FA = (__half*)alloc((size_t)N_NODES * EMB * 2);   // gemm-out table
    __half* GA = (__half*)alloc((size_t)N_NODES * EMB * 2);   // agg-out table
    float*  O  = (float*)d_out;

    // zero deg + cursor (adjacent in ws)
    size_t zspan = (size_t)((char*)row_off - (char*)deg);
    hipMemsetAsync(deg, 0, zspan, stream);

    const int NB_E = (N_EDGES + 255) / 256;   // 1250
    const int AGB  = N_NODES / 4;             // 5000 blocks, wave-per-node

    k_deg<<<NB_E, 256, 0, stream>>>(dst, deg, N_EDGES);
    k_scan<<<1, 1024, 0, stream>>>(deg, row_off, dinv, N_NODES);
    k_scatter<<<NB_E, 256, 0, stream>>>(src, dst, row_off, cursor, dinv,
                                        csr_src, csr_norm, N_EDGES);

    WSplitArgs wa;
    for (int i = 0; i < 6; ++i) { wa.w[i] = w[i]; wa.th[i] = wth[i]; wa.tl[i] = wtl[i]; }
    k_wsplit_all<<<512, 256, 0, stream>>>(wa);

    // conv0 gemm: x @ W0 -> FA
    k_gemm0<<<NTILE, 256, 0, stream>>>(x, wth[0], wtl[0], FA);
    // conv1: agg(FA)+b0,relu -> GA ; GA @ W1 -> FA
    k_agg<<<AGB, 256, 0, stream>>>(FA, row_off, csr_src, csr_norm, dinv, b[0], 1, GA);
    k_gemm<<<NTILE, 256, 0, stream>>>(GA, wth[1], wtl[1], FA);
    // conv2: agg(FA)+b1,relu -> GA ; GA @ W2 -> FA
    k_agg<<<AGB, 256, 0, stream>>>(FA, row_off, csr_src, csr_norm, dinv, b[1], 1, GA);
    k_gemm<<<NTILE, 256, 0, stream>>>(GA, wth[2], wtl[2], FA);
    // conv2 agg (no relu) -> GA ; mlp chain -> d_out
    k_agg<<<AGB, 256, 0, stream>>>(FA, row_off, csr_src, csr_norm, dinv, b[2], 0, GA);
    k_mlp3<<<NTILE, 256, 0, stream>>>(GA,
                                      wth[3], wtl[3], b[3],
                                      wth[4], wtl[4], b[4],
                                      wth[5], wtl[5], b[5],
                                      O);
}